// Round 5
// baseline (218.930 us; speedup 1.0000x reference)
//
#include <hip/hip_runtime.h>
#include <cstddef>

#define D_  32
#define N_  1024
#define T_  256
#define NT_ 1280
#define B_  32
#define RPB 16            // rows per epilogue block (1024 % 16 == 0 -> never crosses s/t row boundary)

// d_ws float layout (total 327,680 floats = 1.31 MB):
//   RA [B][NT][2]  row adj proj, slot=seg_j, bias folded
//   RM [B][NT][2]  row mask proj, slot=seg_j, bias folded
//   CA [2][B][NT]  col adj proj, plane=seg_i
//   CM [2][B][NT]  col mask proj, plane=seg_i
#define RA_OFF 0
#define RM_OFF (B_*NT_*2)
#define CA_OFF (2*B_*NT_*2)
#define CM_OFF (CA_OFF + 2*B_*NT_)

__device__ __forceinline__ float fast_tanh(float x) {
    // tanh(x) = 1 - 2/(e^{2x}+1); saturates to +-1, no NaN paths. err ~1e-6.
    float e = __expf(2.0f * x);
    return 1.0f - 2.0f * __builtin_amdgcn_rcpf(e + 1.0f);
}

__device__ __forceinline__ float dot8(const float4* __restrict__ xv,
                                      const float* __restrict__ w) {
    const float4* wv = (const float4*)w;
    float a = 0.f;
    #pragma unroll
    for (int k = 0; k < D_ / 4; ++k) {
        float4 ww = wv[k];
        a = fmaf(xv[k].x, ww.x, a);
        a = fmaf(xv[k].y, ww.y, a);
        a = fmaf(xv[k].z, ww.z, a);
        a = fmaf(xv[k].w, ww.w, a);
    }
    return a;
}

// One thread per node (b, idx): computes all 8 projections.
// rel(si,sj): ss=0 (0,0), tt=1 (1,1), st=2 (0,1), ts=3 (1,0).
__global__ __launch_bounds__(256) void proj_kernel(
    const float* __restrict__ S,  const float* __restrict__ Tn,
    const float* __restrict__ Wr, const float* __restrict__ br,
    const float* __restrict__ Wm, const float* __restrict__ bm,
    float* __restrict__ ws)
{
    const int idx = blockIdx.x * 256 + threadIdx.x;   // node 0..1279
    const int b   = blockIdx.y;
    const int seg = (idx >= N_);                      // this node's region
    const float* x = seg ? (Tn + ((size_t)b * T_ + (idx - N_)) * D_)
                         : (S  + ((size_t)b * N_ +  idx      ) * D_);
    float4 xv[D_ / 4];
    #pragma unroll
    for (int k = 0; k < D_ / 4; ++k) xv[k] = ((const float4*)x)[k];

    // --- as a ROW i (si=seg): slot sj=0 -> rel(seg,0); sj=1 -> rel(seg,1) ---
    const int rr0 = seg ? 3 : 0;     // rel(seg,0): ts / ss
    const int rr1 = seg ? 1 : 2;     // rel(seg,1): tt / st
    float* RA = ws + RA_OFF;  float* RM = ws + RM_OFF;
    const size_t ri = ((size_t)b * NT_ + idx) * 2;
    RA[ri + 0] = dot8(xv, Wr + rr0 * 2 * D_) + br[rr0];   // row half [:D]
    RA[ri + 1] = dot8(xv, Wr + rr1 * 2 * D_) + br[rr1];
    RM[ri + 0] = dot8(xv, Wm + rr0 * 2 * D_) + bm[rr0];
    RM[ri + 1] = dot8(xv, Wm + rr1 * 2 * D_) + bm[rr1];

    // --- as a COL j (sj=seg): plane si=0 -> rel(0,seg); si=1 -> rel(1,seg) ---
    const int rc0 = seg ? 2 : 0;     // rel(0,seg): st / ss
    const int rc1 = seg ? 1 : 3;     // rel(1,seg): tt / ts
    float* CA = ws + CA_OFF;  float* CM = ws + CM_OFF;
    const size_t ci = (size_t)b * NT_ + idx;
    CA[0 * B_ * NT_ + ci] = dot8(xv, Wr + rc0 * 2 * D_ + D_);   // col half [D:]
    CA[1 * B_ * NT_ + ci] = dot8(xv, Wr + rc1 * 2 * D_ + D_);
    CM[0 * B_ * NT_ + ci] = dot8(xv, Wm + rc0 * 2 * D_ + D_);
    CM[1 * B_ * NT_ + ci] = dot8(xv, Wm + rc1 * 2 * D_ + D_);
}

// Fat-block streaming epilogue: block (320 thr, 5 waves) owns RPB=16 consecutive
// full rows = 80KB contiguous output. Col projections live in registers for the
// whole block; 16 rows' projections preloaded (uniform addresses -> s_load).
// Fully unrolled row loop = 16 independent compute+store chains, no LDS, no
// syncthreads. Waves 0-3: spatial cols (seg_j=0); wave 4: temporal -> all
// selects wave-uniform.
__global__ __launch_bounds__(320) void epi_kernel(
    const float* __restrict__ ws, float* __restrict__ out)
{
    const int tid   = threadIdx.x;         // 0..319
    const int band  = blockIdx.x;          // 0..79 (16 rows each)
    const int b     = blockIdx.y;          // batch
    const int i0    = band * RPB;
    const int seg_i = (i0 >= N_);
    const int seg_j = (tid >= 256) ? 1 : 0;

    const float* RA = ws + RA_OFF;
    const float* RM = ws + RM_OFF;
    const float* CA = ws + CA_OFF;
    const float* CM = ws + CM_OFF;

    // col values: fixed per thread for all 16 rows
    const int j = tid * 4;
    const size_t cbase = ((size_t)seg_i * B_ + b) * NT_ + j;
    const float4 ca = *(const float4*)&CA[cbase];
    const float4 cm = *(const float4*)&CM[cbase];

    // row values: uniform-address loads (block-uniform -> scalarizable), then
    // one per-lane select into registers
    float ra[RPB], rm[RPB];
    #pragma unroll
    for (int k = 0; k < RPB; ++k) {
        const float2 a2 = *(const float2*)&RA[((size_t)b * NT_ + i0 + k) * 2];
        const float2 m2 = *(const float2*)&RM[((size_t)b * NT_ + i0 + k) * 2];
        ra[k] = seg_j ? a2.y : a2.x;
        rm[k] = seg_j ? m2.y : m2.x;
    }

    float* outp = out + ((size_t)(b * NT_ + i0)) * NT_ + j;
    #pragma unroll
    for (int k = 0; k < RPB; ++k) {
        float4 o;
        o.x = fast_tanh((ra[k] + ca.x) * fmaxf(rm[k] + cm.x, 0.f));
        o.y = fast_tanh((ra[k] + ca.y) * fmaxf(rm[k] + cm.y, 0.f));
        o.z = fast_tanh((ra[k] + ca.z) * fmaxf(rm[k] + cm.z, 0.f));
        o.w = fast_tanh((ra[k] + ca.w) * fmaxf(rm[k] + cm.w, 0.f));
        *(float4*)(outp + (size_t)k * NT_) = o;   // block writes 80KB contiguous
    }
}

extern "C" void kernel_launch(void* const* d_in, const int* in_sizes, int n_in,
                              void* d_out, int out_size, void* d_ws, size_t ws_size,
                              hipStream_t stream) {
    const float* S  = (const float*)d_in[0];  // spatial_nodes  [32,1024,32]
    const float* Tn = (const float*)d_in[1];  // temporal_nodes [32,256,32]
    const float* Wr = (const float*)d_in[2];  // W_rel  [4,64]
    const float* br = (const float*)d_in[3];  // b_rel  [4]
    const float* Wm = (const float*)d_in[4];  // W_mask [4,64]
    const float* bm = (const float*)d_in[5];  // b_mask [4]
    float* out = (float*)d_out;               // [32,1280,1280] fp32
    float* ws  = (float*)d_ws;                // needs 1.31 MB

    proj_kernel<<<dim3(NT_ / 256, B_), 256, 0, stream>>>(S, Tn, Wr, br, Wm, bm, ws);
    epi_kernel <<<dim3(NT_ / RPB, B_),  320, 0, stream>>>(ws, out);
}